// Round 1
// baseline (738.075 us; speedup 1.0000x reference)
//
#include <hip/hip_runtime.h>

#define DEVI __device__ __forceinline__

typedef __bf16 bf16;
typedef __attribute__((ext_vector_type(8))) __bf16 bf16x8;
typedef __attribute__((ext_vector_type(4))) float floatx4;

constexpr int Bsz = 8192;   // batch
constexpr int Hd  = 2048;   // hidden
constexpr int INd = 2048;   // input dim
constexpr int Kd  = 4096;   // IN + H (concatenated K)
constexpr int N1  = Bsz * INd;  // 16,777,216 elems: size of each converted array

DEVI unsigned short f2bf_rne(float f) {
  unsigned int u = __float_as_uint(f);
  u += 0x7FFFu + ((u >> 16) & 1u);
  return (unsigned short)(u >> 16);
}

// Convert 4 equal-sized fp32 arrays -> bf16 (as ushort) into ws.
__global__ void cvt4(const float* __restrict__ s0, const float* __restrict__ s1,
                     const float* __restrict__ s2, const float* __restrict__ s3,
                     unsigned short* __restrict__ dst) {
  const float* src = (blockIdx.y == 0) ? s0 : (blockIdx.y == 1) ? s1
                   : (blockIdx.y == 2) ? s2 : s3;
  unsigned short* out = dst + (size_t)blockIdx.y * N1;
  const int nv = N1 / 4;
  for (int i = blockIdx.x * blockDim.x + threadIdx.x; i < nv;
       i += gridDim.x * blockDim.x) {
    float4 v = ((const float4*)src)[i];
    ushort4 o;
    o.x = f2bf_rne(v.x); o.y = f2bf_rne(v.y);
    o.z = f2bf_rne(v.z); o.w = f2bf_rne(v.w);
    ((ushort4*)out)[i] = o;
  }
}

DEVI void gload_lds16(const void* g, void* l) {
  __builtin_amdgcn_global_load_lds(
      (const __attribute__((address_space(1))) void*)g,
      (__attribute__((address_space(3))) void*)l, 16, 0, 0);
}

DEVI float sigm(float x) { return 1.0f / (1.0f + __expf(-x)); }

// 128 (batch rows) x 128 (4 gates x 32 h-cols) tile, BK=64, 4 waves.
// Wave w computes rows [w*32, w*32+32) x all 128 cols -> epilogue lane-local.
__global__ void lstm_gemm(const unsigned short* __restrict__ ws,
                          const float* __restrict__ bias,
                          const float* __restrict__ c_prev,
                          float* __restrict__ out_h,
                          float* __restrict__ out_c) {
  constexpr int BK = 64;
  __shared__ __align__(16) unsigned short sA[128][BK];
  __shared__ __align__(16) unsigned short sB[128][BK];

  const unsigned short* xb  = ws;
  const unsigned short* hb  = ws + (size_t)N1;
  const unsigned short* wih = ws + (size_t)2 * N1;
  const unsigned short* whh = ws + (size_t)3 * N1;

  const int tid  = threadIdx.x;
  const int lane = tid & 63;
  const int w    = tid >> 6;     // wave 0..3
  const int lr   = lane & 15;
  const int lk   = lane >> 4;

  const int rb = blockIdx.y * 128;   // batch row base
  const int bc = blockIdx.x;         // h-col tile index (32 cols per tile)

  floatx4 acc[2][8];
#pragma unroll
  for (int i = 0; i < 2; ++i)
#pragma unroll
    for (int j = 0; j < 8; ++j)
      acc[i][j] = (floatx4){0.f, 0.f, 0.f, 0.f};

  const int sRow  = (lane >> 3);      // 0..7 within 8-row staging chunk
  const int sCol8 = (lane & 7) * 8;   // bf16 col offset within row

  for (int k0 = 0; k0 < Kd; k0 += BK) {
    const bool first = (k0 < INd);
    const unsigned short* aS = first ? xb : hb;
    const unsigned short* bS = first ? wih : whh;
    const int kk = first ? k0 : (k0 - INd);

    // Stage A: tile rows [w*32, w*32+32), 8 rows per instruction.
#pragma unroll
    for (int t = 0; t < 4; ++t) {
      const int trow = w * 32 + t * 8;
      const unsigned short* g =
          aS + (size_t)(rb + trow + sRow) * INd + kk + sCol8;
      gload_lds16(g, (char*)&sA[0][0] + (size_t)trow * (BK * 2));
    }
    // Stage B: tile rows n in [w*32, w*32+32)  (gate g == w),
    // weight row = w*2048 + bc*32 + (n & 31).
#pragma unroll
    for (int t = 0; t < 4; ++t) {
      const int trow = w * 32 + t * 8;
      const unsigned short* g =
          bS + (size_t)(w * Hd + bc * 32 + t * 8 + sRow) * INd + kk + sCol8;
      gload_lds16(g, (char*)&sB[0][0] + (size_t)trow * (BK * 2));
    }

    __syncthreads();  // drains vmcnt before barrier (compiler-emitted)

#pragma unroll
    for (int kkf = 0; kkf < 2; ++kkf) {
      const int kof = kkf * 32 + lk * 8;
      bf16x8 a0 = *(const bf16x8*)&sA[w * 32 + 0 * 16 + lr][kof];
      bf16x8 a1 = *(const bf16x8*)&sA[w * 32 + 1 * 16 + lr][kof];
#pragma unroll
      for (int ni = 0; ni < 8; ++ni) {
        bf16x8 b = *(const bf16x8*)&sB[ni * 16 + lr][kof];
        acc[0][ni] = __builtin_amdgcn_mfma_f32_16x16x32_bf16(a0, b, acc[0][ni], 0, 0, 0);
        acc[1][ni] = __builtin_amdgcn_mfma_f32_16x16x32_bf16(a1, b, acc[1][ni], 0, 0, 0);
      }
    }
    __syncthreads();
  }

  // Epilogue: lane-local LSTM. Fragment ni covers gate (ni>>1), col-half (ni&1).
  const int hcolb = bc * 32;
#pragma unroll
  for (int ci = 0; ci < 2; ++ci) {
    const int hcol = hcolb + ci * 16 + lr;
    const float bi = bias[0 * Hd + hcol];
    const float bf = bias[1 * Hd + hcol];
    const float bj = bias[2 * Hd + hcol];
    const float bo = bias[3 * Hd + hcol];
#pragma unroll
    for (int mi = 0; mi < 2; ++mi) {
#pragma unroll
      for (int r = 0; r < 4; ++r) {
        const int row = rb + w * 32 + mi * 16 + lk * 4 + r;
        const float gi = acc[mi][ci + 0][r] + bi;
        const float gf = acc[mi][ci + 2][r] + bf;
        const float gj = acc[mi][ci + 4][r] + bj;
        const float go = acc[mi][ci + 6][r] + bo;
        const float iv = sigm(gi);
        const float fv = sigm(gf);
        const float jv = tanhf(gj);
        const float ov = sigm(go);
        const size_t idx = (size_t)row * Hd + hcol;
        const float cp = c_prev[idx];
        const float cv = fv * cp + fminf(1.0f - fv, iv) * jv;
        const float hv = ov * tanhf(cv);
        out_h[idx] = hv;
        out_c[idx] = cv;
      }
    }
  }
}

extern "C" void kernel_launch(void* const* d_in, const int* in_sizes, int n_in,
                              void* d_out, int out_size, void* d_ws, size_t ws_size,
                              hipStream_t stream) {
  const float* x      = (const float*)d_in[0];
  const float* h_prev = (const float*)d_in[1];
  const float* c_prev = (const float*)d_in[2];
  const float* w_ih   = (const float*)d_in[3];
  const float* w_hh   = (const float*)d_in[4];
  const float* bias   = (const float*)d_in[5];

  float* out_h = (float*)d_out;
  float* out_c = out_h + (size_t)Bsz * Hd;
  unsigned short* wsb = (unsigned short*)d_ws;

  // Convert the four fp32 operand arrays to bf16 in workspace (134 MB).
  dim3 cgrid(2048, 4);
  cvt4<<<cgrid, 256, 0, stream>>>(x, h_prev, w_ih, w_hh, wsb);

  // Fused GEMM + LSTM epilogue.
  dim3 grid(Hd / 32, Bsz / 128);  // 64 x 64 tiles
  lstm_gemm<<<grid, 256, 0, stream>>>(wsb, bias, c_prev, out_h, out_c);
}

// Round 2
// 623.907 us; speedup vs baseline: 1.1830x; 1.1830x over previous
//
#include <hip/hip_runtime.h>

#define DEVI __device__ __forceinline__

typedef __bf16 bf16;
typedef __attribute__((ext_vector_type(8))) __bf16 bf16x8;
typedef __attribute__((ext_vector_type(4))) float floatx4;

constexpr int Bsz = 8192;   // batch
constexpr int Hd  = 2048;   // hidden
constexpr int INd = 2048;   // input dim
constexpr int Kd  = 4096;   // IN + H (concatenated K)
constexpr int N1  = Bsz * INd;  // elems per converted array

DEVI unsigned short f2bf_rne(float f) {
  unsigned int u = __float_as_uint(f);
  u += 0x7FFFu + ((u >> 16) & 1u);
  return (unsigned short)(u >> 16);
}

// Convert 4 equal-sized fp32 arrays -> bf16 (as ushort) into ws.
__global__ void cvt4(const float* __restrict__ s0, const float* __restrict__ s1,
                     const float* __restrict__ s2, const float* __restrict__ s3,
                     unsigned short* __restrict__ dst) {
  const float* src = (blockIdx.y == 0) ? s0 : (blockIdx.y == 1) ? s1
                   : (blockIdx.y == 2) ? s2 : s3;
  unsigned short* out = dst + (size_t)blockIdx.y * N1;
  const int nv = N1 / 4;
  for (int i = blockIdx.x * blockDim.x + threadIdx.x; i < nv;
       i += gridDim.x * blockDim.x) {
    float4 v = ((const float4*)src)[i];
    ushort4 o;
    o.x = f2bf_rne(v.x); o.y = f2bf_rne(v.y);
    o.z = f2bf_rne(v.z); o.w = f2bf_rne(v.w);
    ((ushort4*)out)[i] = o;
  }
}

DEVI void gload_lds16(const void* g, void* l) {
  __builtin_amdgcn_global_load_lds(
      (const __attribute__((address_space(1))) void*)g,
      (__attribute__((address_space(3))) void*)l, 16, 0, 0);
}

DEVI float sigm(float x) { return 1.0f / (1.0f + __expf(-x)); }

// 128 (batch rows) x 128 (4 gates x 32 h-cols) tile, BK=64, 4 waves.
// LDS tiles are XOR-swizzled per 16B chunk: physical chunk p at row r holds
// logical chunk p ^ (r & 7). Staging achieves this by pre-swizzling the
// per-lane GLOBAL source column (global_load_lds dest is linear, rule #21);
// reads XOR the element offset with (row&7)*8.
__global__ void lstm_gemm(const unsigned short* __restrict__ ws,
                          const float* __restrict__ bias,
                          const float* __restrict__ c_prev,
                          float* __restrict__ out_h,
                          float* __restrict__ out_c) {
  constexpr int BK = 64;
  __shared__ __align__(16) unsigned short sA[128][BK];
  __shared__ __align__(16) unsigned short sB[128][BK];

  const unsigned short* xb  = ws;
  const unsigned short* hb  = ws + (size_t)N1;
  const unsigned short* wih = ws + (size_t)2 * N1;
  const unsigned short* whh = ws + (size_t)3 * N1;

  const int tid  = threadIdx.x;
  const int lane = tid & 63;
  const int w    = tid >> 6;     // wave 0..3
  const int lr   = lane & 15;
  const int lk   = lane >> 4;

  const int rb = blockIdx.y * 128;   // batch row base
  const int bc = blockIdx.x;         // h-col tile index (32 cols per tile)

  floatx4 acc[2][8];
#pragma unroll
  for (int i = 0; i < 2; ++i)
#pragma unroll
    for (int j = 0; j < 8; ++j)
      acc[i][j] = (floatx4){0.f, 0.f, 0.f, 0.f};

  const int sRow   = lane >> 3;                      // 0..7 row within chunk
  const int sColSw = (((lane & 7) ^ sRow) * 8);      // swizzled source chunk

  for (int k0 = 0; k0 < Kd; k0 += BK) {
    const bool first = (k0 < INd);
    const unsigned short* aS = first ? xb : hb;
    const unsigned short* bS = first ? wih : whh;
    const int kk = first ? k0 : (k0 - INd);

    // Stage A: tile rows [w*32, w*32+32), 8 rows per instruction.
#pragma unroll
    for (int t = 0; t < 4; ++t) {
      const int trow = w * 32 + t * 8;
      const unsigned short* g =
          aS + (size_t)(rb + trow + sRow) * INd + kk + sColSw;
      gload_lds16(g, (char*)&sA[0][0] + (size_t)trow * (BK * 2));
    }
    // Stage B: tile rows n in [w*32, w*32+32)  (gate == w),
    // weight row = w*2048 + bc*32 + (n & 31).
#pragma unroll
    for (int t = 0; t < 4; ++t) {
      const int trow = w * 32 + t * 8;
      const unsigned short* g =
          bS + (size_t)(w * Hd + bc * 32 + t * 8 + sRow) * INd + kk + sColSw;
      gload_lds16(g, (char*)&sB[0][0] + (size_t)trow * (BK * 2));
    }

    __syncthreads();

#pragma unroll
    for (int kkf = 0; kkf < 2; ++kkf) {
      const int kof = kkf * 32 + lk * 8;
      const int sw  = kof ^ ((lr & 7) * 8);   // swizzled read offset (elems)
      bf16x8 a0 = *(const bf16x8*)&sA[w * 32 + 0 * 16 + lr][sw];
      bf16x8 a1 = *(const bf16x8*)&sA[w * 32 + 1 * 16 + lr][sw];
#pragma unroll
      for (int ni = 0; ni < 8; ++ni) {
        bf16x8 b = *(const bf16x8*)&sB[ni * 16 + lr][sw];
        acc[0][ni] = __builtin_amdgcn_mfma_f32_16x16x32_bf16(a0, b, acc[0][ni], 0, 0, 0);
        acc[1][ni] = __builtin_amdgcn_mfma_f32_16x16x32_bf16(a1, b, acc[1][ni], 0, 0, 0);
      }
    }
    __syncthreads();
  }

  // Epilogue: lane-local LSTM. Fragment ni covers gate (ni>>1), col-half (ni&1).
  const int hcolb = bc * 32;
#pragma unroll
  for (int ci = 0; ci < 2; ++ci) {
    const int hcol = hcolb + ci * 16 + lr;
    const float bi = bias[0 * Hd + hcol];
    const float bf = bias[1 * Hd + hcol];
    const float bj = bias[2 * Hd + hcol];
    const float bo = bias[3 * Hd + hcol];
#pragma unroll
    for (int mi = 0; mi < 2; ++mi) {
#pragma unroll
      for (int r = 0; r < 4; ++r) {
        const int row = rb + w * 32 + mi * 16 + lk * 4 + r;
        const float gi = acc[mi][ci + 0][r] + bi;
        const float gf = acc[mi][ci + 2][r] + bf;
        const float gj = acc[mi][ci + 4][r] + bj;
        const float go = acc[mi][ci + 6][r] + bo;
        const float iv = sigm(gi);
        const float fv = sigm(gf);
        const float jv = tanhf(gj);
        const float ov = sigm(go);
        const size_t idx = (size_t)row * Hd + hcol;
        const float cp = c_prev[idx];
        const float cv = fv * cp + fminf(1.0f - fv, iv) * jv;
        const float hv = ov * tanhf(cv);
        out_h[idx] = hv;
        out_c[idx] = cv;
      }
    }
  }
}

extern "C" void kernel_launch(void* const* d_in, const int* in_sizes, int n_in,
                              void* d_out, int out_size, void* d_ws, size_t ws_size,
                              hipStream_t stream) {
  const float* x      = (const float*)d_in[0];
  const float* h_prev = (const float*)d_in[1];
  const float* c_prev = (const float*)d_in[2];
  const float* w_ih   = (const float*)d_in[3];
  const float* w_hh   = (const float*)d_in[4];
  const float* bias   = (const float*)d_in[5];

  float* out_h = (float*)d_out;
  float* out_c = out_h + (size_t)Bsz * Hd;
  unsigned short* wsb = (unsigned short*)d_ws;

  dim3 cgrid(2048, 4);
  cvt4<<<cgrid, 256, 0, stream>>>(x, h_prev, w_ih, w_hh, wsb);

  dim3 grid(Hd / 32, Bsz / 128);  // 64 x 64 tiles
  lstm_gemm<<<grid, 256, 0, stream>>>(wsb, bias, c_prev, out_h, out_c);
}